// Round 12
// baseline (480.443 us; speedup 1.0000x reference)
//
#include <hip/hip_runtime.h>
#include <hip/hip_bf16.h>

typedef __hip_bfloat16 bf16;
typedef unsigned short u16;
typedef __attribute__((ext_vector_type(8))) short short8;
typedef __attribute__((ext_vector_type(4))) short s4v;
typedef __attribute__((ext_vector_type(4))) float f32x4;
typedef __attribute__((ext_vector_type(4))) unsigned int u32x4;

#define LEAK 0.1f
#define EPS_ 1e-5f
#define MFMA(a, b, c) __builtin_amdgcn_mfma_f32_16x16x32_bf16(a, b, c, 0, 0, 0)
// N=32 C=64 T=400 V=27 S=2 IC=16 O=64; P = T*V = 10800 per n.

__device__ __forceinline__ float u2f(u16 u) { return __uint_as_float(((unsigned int)u) << 16); }
__device__ __forceinline__ u16 f2u(float f) {
  bf16 h = __float2bfloat16(f);
  u16 r;
  __builtin_memcpy(&r, &h, 2);
  return r;
}
__device__ __forceinline__ f32x4 z4() { f32x4 z = {0.f, 0.f, 0.f, 0.f}; return z; }

// ---------------------------------------------------------------------------
// G1+G2a FUSED. r10 change: staging via f32x4 (thread = (c, 4 consecutive
// pl)) — 14 vector loads/thread instead of 56 scalar (validated mechanism
// from g_ab r9). GEMM/logit phases unchanged.
// ---------------------------------------------------------------------------
__global__ __launch_bounds__(512, 2) void g_qk_att(
    const float* __restrict__ x, const float* __restrict__ pe,
    const float* __restrict__ W_in, const float* __restrict__ b_in,
    float* __restrict__ att)
{
  __shared__ __align__(16) u16 sB16[14 * 2 * 64 * 8];  // staged (x+pe) pre-frag
  __shared__ __align__(16) u16 sQF[2][32][136];        // q^T pre-frag [s][u][k]
  __shared__ __align__(16) u16 sKF[2][32][136];        // k^T pre-frag [s][v][k]
  const int tid = threadIdx.x;
  const int w = tid >> 6, lane = tid & 63;
  const int m = lane & 15, quad = lane >> 4;
  const int ot = w & 3, g = w >> 2;
  const int n = blockIdx.y;
  const int p0 = blockIdx.x * 216;  // 8 t-slices * 27

  short8 aW[2];
#pragma unroll
  for (int kf = 0; kf < 2; ++kf) {
    short8 tt;
#pragma unroll
    for (int j = 0; j < 8; ++j)
      tt[j] = (short)f2u(W_in[(16 * ot + m) * 64 + 32 * kf + 8 * quad + j]);
    aW[kf] = tt;
  }
  float bb[4];
#pragma unroll
  for (int r = 0; r < 4; ++r) bb[r] = b_in[16 * ot + quad * 4 + r];

  // stage: 3456 units of (c, 4 pl); f32x4 loads (16B-aligned: 10800,216,pl%4
  // all divisible by 4). pl always < 216 (no tail).
#pragma unroll
  for (int i = 0; i < 7; ++i) {
    int unit = i * 512 + tid;
    if (unit < 3456) {
      int c = unit / 54, p4 = unit - c * 54;
      int pl = p4 * 4;
      f32x4 xv = *(const f32x4*)&x[(n * 64 + c) * 10800 + p0 + pl];
      f32x4 pv = *(const f32x4*)&pe[c * 10800 + p0 + pl];
      int kf = c >> 5, qq = (c >> 3) & 3, j = c & 7;
      int tile = pl >> 4, mm = pl & 15;
#pragma unroll
      for (int e = 0; e < 4; ++e)
        sB16[(((tile * 2 + kf) * 64) + qq * 16 + mm + e) * 8 + j] = f2u(xv[e] + pv[e]);
    }
  }
  __syncthreads();

  u16* dstF = (ot < 2 ? &sQF[0][0][0] : &sKF[0][0][0]) + (ot & 1) * 32 * 136;
#pragma unroll
  for (int ti = 0; ti < 7; ++ti) {
    int tile = 7 * g + ti;
    short8 b0 = *(const short8*)&sB16[((tile * 2 + 0) * 64 + lane) * 8];
    short8 b1 = *(const short8*)&sB16[((tile * 2 + 1) * 64 + lane) * 8];
    f32x4 acc = MFMA(aW[0], b0, z4());
    acc = MFMA(aW[1], b1, acc);
    int pl = tile * 16 + m;
    if (pl < 216) {
      int tl = pl / 27, u = pl - tl * 27;
      s4v pk;
#pragma unroll
      for (int reg = 0; reg < 4; ++reg) pk[reg] = (short)f2u(acc[reg] + bb[reg]);
      *(s4v*)&dstF[u * 136 + tl * 16 + quad * 4] = pk;
    }
  }
  __syncthreads();

  {
    const int s = w & 1, ut = (w >> 1) & 1, vt = w >> 2;
    f32x4 acc = z4();
#pragma unroll
    for (int ks = 0; ks < 4; ++ks) {
      short8 a = *(const short8*)&sQF[s][ut * 16 + m][ks * 32 + quad * 8];
      short8 b = *(const short8*)&sKF[s][vt * 16 + m][ks * 32 + quad * 8];
      acc = MFMA(a, b, acc);
    }
#pragma unroll
    for (int reg = 0; reg < 4; ++reg) {
      int u = ut * 16 + quad * 4 + reg, v = vt * 16 + m;
      if (u < 27 && v < 27)
        atomicAdd(&att[(n * 2 + s) * 729 + u * 27 + v], acc[reg]);
    }
  }
}

// ---------------------------------------------------------------------------
// G2b: att = tanh(acc/6400)*alphas[s] + att0[s,u,v]   (in place)
// ---------------------------------------------------------------------------
__global__ __launch_bounds__(256) void k_att_fin(
    float* __restrict__ att, const float* __restrict__ alphas,
    const float* __restrict__ att0)
{
  int i = blockIdx.x * 256 + threadIdx.x;
  if (i >= 32 * 2 * 729) return;
  int s = (i / 729) & 1;
  int r = i % 729;
  att[i] = tanhf(att[i] * (1.f / 6400.f)) * alphas[s] + att0[s * 729 + r];
}

// ---------------------------------------------------------------------------
// G3+G4 MERGED (g_abcd): block = (n, 4 center t), 6 staged slices (1 halo
// each side, zero-padded). Phase-sequential, 4 barriers:
//   P1 stage x f32 (coalesced, r9-validated) | P2 y2 = x.att (6 sl)
//   | P3 y3 = lrelu(x+bn(Wout@y2)) -> LDS pre-frag (6 sl)
//   | P4 y4 = lrelu(x+bn(Wff@y3)) -> LDS pre-frag (6 sl, aliases sy2f)
//   | P5 z = lrelu(y4 + bn(conv3(y4))) -> out (4 slices)
// Eliminates the y3T 88 MB HBM round-trip + one kernel launch. Halo y3/y4
// recomputed (1.5x on tiny GEMMs). All pre-frag index algebra identical to
// the verified r9 writers (kfp=ot>>1 [or 2s+(ot>>1) for K=128], qp, q1).
// LDS 112.75 KB (static >64KB verified on gfx950 per the 128KB 8-phase
// example) -> 1 block/CU. Weight frags loaded per-phase to cap VGPR.
// Uninit sy3f cols v>=27 feed only discarded MFMA columns (col-independent).
// ---------------------------------------------------------------------------
__global__ __launch_bounds__(512, 2) void g_abcd(
    const float* __restrict__ x, const float* __restrict__ att,
    const float* __restrict__ W_out, const float* __restrict__ b_out,
    const float* __restrict__ g_out, const float* __restrict__ be_out,
    const float* __restrict__ m_out, const float* __restrict__ v_out,
    const float* __restrict__ W_ff, const float* __restrict__ b_ff,
    const float* __restrict__ g_ff, const float* __restrict__ be_ff,
    const float* __restrict__ m_ff, const float* __restrict__ v_ff,
    const float* __restrict__ W_t, const float* __restrict__ b_t,
    const float* __restrict__ g_t, const float* __restrict__ be_t,
    const float* __restrict__ m_t, const float* __restrict__ v_t,
    float* __restrict__ out)
{
  __shared__ __align__(16) char smem[115456];
  float* sxf = (float*)smem;                     // [64][163] f32, cols 0..161
  u32x4* sy2f = (u32x4*)(smem + 41728);          // [6][2][4][64]  P2->P3
  u32x4* sy4f = (u32x4*)(smem + 41728);          // [6][2][2][64]  alias, P4->P5
  u32x4* sy3f = (u32x4*)(smem + 41728 + 49152);  // [6][2][2][64]  P3->P4
#define IDX2(sl, nt, kfp, ln) ((((sl)*2 + (nt)) * 4 + (kfp)) * 64 + (ln))
#define IDX3(sl, vt, kf, ln) ((((sl)*2 + (vt)) * 2 + (kf)) * 64 + (ln))
  const int tid = threadIdx.x;
  const int w = tid >> 6, lane = tid & 63;
  const int m = lane & 15, quad = lane >> 4;
  const int ot = w & 3, g = w >> 2;
  const int n = blockIdx.y, t0 = blockIdx.x * 4;

  const int q1 = quad & 1;
  const int qp = (2 * ot + (quad >> 1)) & 3;

  // P1: stage x for slices t0-1 .. t0+4 (zero-clipped), coalesced scalar
  {
    int base = t0 * 27 - 27;
    for (int i = tid; i < 10368; i += 512) {
      int c = i / 162, r = i - c * 162;
      int gg = base + r;
      sxf[c * 163 + r] = (gg >= 0 && gg < 10800) ? x[(n * 64 + c) * 10800 + gg] : 0.f;
    }
  }
  // att B-frags from global (5.8KB region, L1/L2-hot)  [verified pattern]
  short8 bAtt[4];
#pragma unroll
  for (int s = 0; s < 2; ++s)
#pragma unroll
    for (int nt = 0; nt < 2; ++nt) {
      short8 tt;
#pragma unroll
      for (int j = 0; j < 8; ++j) {
        int u = 8 * quad + j, v = 16 * nt + m;
        tt[j] = (u < 27 && v < 27) ? (short)f2u(att[(n * 2 + s) * 729 + u * 27 + v]) : (short)0;
      }
      bAtt[s * 2 + nt] = tt;
    }
  __syncthreads();

  // P2: y2 frags for 6 slices; group g handles sl = g, g+2, g+4
#pragma unroll
  for (int li = 0; li < 3; ++li) {
    int sl = 2 * li + g;
    int t = t0 - 1 + sl;
    if (t < 0 || t >= 400) continue;  // y2/y3 of invalid slice never read
    short8 ax;
#pragma unroll
    for (int j = 0; j < 8; ++j) {
      int u = quad * 8 + j;
      ax[j] = (u < 27) ? (short)f2u(sxf[(16 * ot + m) * 163 + sl * 27 + u]) : (short)0;
    }
    f32x4 acc[4];
#pragma unroll
    for (int f = 0; f < 4; ++f) acc[f] = MFMA(ax, bAtt[f], z4());
#pragma unroll
    for (int s = 0; s < 2; ++s)
#pragma unroll
      for (int nt = 0; nt < 2; ++nt) {
        f32x4 a = acc[s * 2 + nt];
        s4v pk;
#pragma unroll
        for (int reg = 0; reg < 4; ++reg) pk[reg] = (short)f2u(a[reg]);
        *(s4v*)((u16*)&sy2f[IDX2(sl, nt, 2 * s + (ot >> 1), qp * 16 + m)] + 4 * q1) = pk;
      }
  }
  __syncthreads();

  // P3: y3 for 6 slices -> sy3f pre-frag
  {
    short8 aWo[4];
#pragma unroll
    for (int kf = 0; kf < 4; ++kf) {
      short8 tt;
#pragma unroll
      for (int j = 0; j < 8; ++j)
        tt[j] = (short)f2u(W_out[(16 * ot + m) * 128 + 32 * kf + 8 * quad + j]);
      aWo[kf] = tt;
    }
    float Ao[4], Bo[4];
#pragma unroll
    for (int reg = 0; reg < 4; ++reg) {
      int o = 16 * ot + quad * 4 + reg;
      float sc = g_out[o] * rsqrtf(v_out[o] + EPS_);
      Ao[reg] = sc;
      Bo[reg] = (b_out[o] - m_out[o]) * sc + be_out[o];
    }
#pragma unroll
    for (int li = 0; li < 3; ++li) {
      int sl = 2 * li + g;
      int t = t0 - 1 + sl;
      if (t < 0 || t >= 400) continue;
#pragma unroll
      for (int vt = 0; vt < 2; ++vt) {
        f32x4 a0 = z4();
#pragma unroll
        for (int kf = 0; kf < 4; ++kf) {
          short8 b = *(const short8*)&sy2f[IDX2(sl, vt, kf, lane)];
          a0 = MFMA(aWo[kf], b, a0);
        }
        int v = vt * 16 + m;
        if (v < 27) {
          s4v pk;
#pragma unroll
          for (int reg = 0; reg < 4; ++reg) {
            int o = 16 * ot + quad * 4 + reg;
            float r = sxf[o * 163 + sl * 27 + v] + a0[reg] * Ao[reg] + Bo[reg];
            pk[reg] = (short)f2u((r >= 0.f) ? r : LEAK * r);
          }
          *(s4v*)((u16*)&sy3f[IDX3(sl, vt, ot >> 1, qp * 16 + m)] + 4 * q1) = pk;
        }
      }
    }
  }
  __syncthreads();

  // P4: y4 for 6 slices -> sy4f pre-frag (aliases sy2f; sy2f dead)
  {
    short8 aWf[2];
#pragma unroll
    for (int kf = 0; kf < 2; ++kf) {
      short8 tt;
#pragma unroll
      for (int j = 0; j < 8; ++j)
        tt[j] = (short)f2u(W_ff[(16 * ot + m) * 64 + 32 * kf + 8 * quad + j]);
      aWf[kf] = tt;
    }
    float Af[4], Bf[4];
#pragma unroll
    for (int reg = 0; reg < 4; ++reg) {
      int o = 16 * ot + quad * 4 + reg;
      float sc = g_ff[o] * rsqrtf(v_ff[o] + EPS_);
      Af[reg] = sc;
      Bf[reg] = (b_ff[o] - m_ff[o]) * sc + be_ff[o];
    }
#pragma unroll
    for (int li = 0; li < 3; ++li) {
      int sl = 2 * li + g;
      int t = t0 - 1 + sl;
      if (t >= 0 && t < 400) {
#pragma unroll
        for (int vt = 0; vt < 2; ++vt) {
          short8 yb0 = *(const short8*)&sy3f[IDX3(sl, vt, 0, lane)];
          short8 yb1 = *(const short8*)&sy3f[IDX3(sl, vt, 1, lane)];
          f32x4 acc = MFMA(aWf[0], yb0, z4());
          acc = MFMA(aWf[1], yb1, acc);
          int v = vt * 16 + m;
          s4v pk;
#pragma unroll
          for (int reg = 0; reg < 4; ++reg) {
            int o = 16 * ot + quad * 4 + reg;
            float xr = (v < 27) ? sxf[o * 163 + sl * 27 + v] : 0.f;
            float r = xr + acc[reg] * Af[reg] + Bf[reg];
            pk[reg] = (short)f2u((r >= 0.f) ? r : LEAK * r);
          }
          *(s4v*)((u16*)&sy4f[IDX3(sl, vt, ot >> 1, qp * 16 + m)] + 4 * q1) = pk;
        }
      } else {
        s4v zz = {0, 0, 0, 0};
#pragma unroll
        for (int vt = 0; vt < 2; ++vt)
          *(s4v*)((u16*)&sy4f[IDX3(sl, vt, ot >> 1, qp * 16 + m)] + 4 * q1) = zz;
      }
    }
  }
  __syncthreads();

  // P5: conv + residual; group g handles tc = g, g+2 (4 outputs total)
  {
    short8 aWt[6];
#pragma unroll
    for (int kf = 0; kf < 6; ++kf) {  // k = dt*64 + i   [verified pattern]
      short8 tt;
      int dt = kf >> 1;
#pragma unroll
      for (int j = 0; j < 8; ++j) {
        int ii = 32 * (kf & 1) + 8 * quad + j;
        tt[j] = (short)f2u(W_t[((16 * ot + m) * 64 + ii) * 3 + dt]);
      }
      aWt[kf] = tt;
    }
    float At[4], Bt[4];
#pragma unroll
    for (int reg = 0; reg < 4; ++reg) {
      int o = 16 * ot + quad * 4 + reg;
      float sc = g_t[o] * rsqrtf(v_t[o] + EPS_);
      At[reg] = sc;
      Bt[reg] = (b_t[o] - m_t[o]) * sc + be_t[o];
    }
#pragma unroll
    for (int ci = 0; ci < 2; ++ci) {
      int tc = 2 * ci + g;
      int t = t0 + tc;
#pragma unroll
      for (int vt = 0; vt < 2; ++vt) {
        f32x4 acc = z4();
#pragma unroll
        for (int kf = 0; kf < 6; ++kf) {
          short8 b = *(const short8*)&sy4f[IDX3(tc + (kf >> 1), vt, kf & 1, lane)];
          acc = MFMA(aWt[kf], b, acc);
        }
        int v = vt * 16 + m;
        if (v < 27) {
          s4v res = *(const s4v*)((const u16*)&sy4f[IDX3(tc + 1, vt, ot >> 1, qp * 16 + m)] + 4 * q1);
#pragma unroll
          for (int reg = 0; reg < 4; ++reg) {
            int o = 16 * ot + quad * 4 + reg;
            float r = u2f((u16)res[reg]) + acc[reg] * At[reg] + Bt[reg];
            out[((n * 64 + o) * 400 + t) * 27 + v] = (r >= 0.f) ? r : LEAK * r;
          }
        }
      }
    }
  }
#undef IDX2
#undef IDX3
}

// ---------------------------------------------------------------------------
extern "C" void kernel_launch(void* const* d_in, const int* in_sizes, int n_in,
                              void* d_out, int out_size, void* d_ws, size_t ws_size,
                              hipStream_t stream)
{
  const float* x      = (const float*)d_in[0];
  const float* pe     = (const float*)d_in[1];
  const float* W_in   = (const float*)d_in[2];
  const float* b_in   = (const float*)d_in[3];
  const float* alphas = (const float*)d_in[4];
  const float* att0   = (const float*)d_in[5];
  const float* W_out  = (const float*)d_in[6];
  const float* b_out  = (const float*)d_in[7];
  const float* g_out  = (const float*)d_in[8];
  const float* be_out = (const float*)d_in[9];
  const float* m_out  = (const float*)d_in[10];
  const float* v_out  = (const float*)d_in[11];
  const float* W_ff   = (const float*)d_in[12];
  const float* b_ff   = (const float*)d_in[13];
  const float* g_ff   = (const float*)d_in[14];
  const float* be_ff  = (const float*)d_in[15];
  const float* m_ff   = (const float*)d_in[16];
  const float* v_ff   = (const float*)d_in[17];
  const float* W_t    = (const float*)d_in[18];
  const float* b_t    = (const float*)d_in[19];
  const float* g_t    = (const float*)d_in[20];
  const float* be_t   = (const float*)d_in[21];
  const float* m_t    = (const float*)d_in[22];
  const float* v_t    = (const float*)d_in[23];

  // workspace: att f32 [32][2][27][27] only (y3T eliminated by the merge)
  float* att = (float*)d_ws;

  hipMemsetAsync(att, 0, 32 * 2 * 729 * sizeof(float), stream);
  g_qk_att<<<dim3(50, 32), 512, 0, stream>>>(x, pe, W_in, b_in, att);
  k_att_fin<<<dim3(183), 256, 0, stream>>>(att, alphas, att0);
  g_abcd<<<dim3(100, 32), 512, 0, stream>>>(
      x, att,
      W_out, b_out, g_out, be_out, m_out, v_out,
      W_ff, b_ff, g_ff, be_ff, m_ff, v_ff,
      W_t, b_t, g_t, be_t, m_t, v_t, (float*)d_out);
}